// Round 5
// baseline (470.871 us; speedup 1.0000x reference)
//
#include <hip/hip_runtime.h>

#define THICKNESS 0.00047f

typedef float f4 __attribute__((ext_vector_type(4)));
typedef int   i4 __attribute__((ext_vector_type(4)));

#define NT_LOAD(p) __builtin_nontemporal_load(p)

// K1: 4 faces/thread. Gather + StVK energy -> ws_e[f]; block-reduced loss.
// NO per-vertex atomics here (they move to K2 so rocprof decomposes the cost).
__global__ __launch_bounds__(256) void energy_k1(
    const float* __restrict__ pred_pos,    // [V,3]
    const int*   __restrict__ faces,       // [F,3]
    const float* __restrict__ Dm_inv,      // [F,2,2]
    const float* __restrict__ f_area,      // [F,1]
    const float* __restrict__ lame_mu,     // [1]
    const float* __restrict__ lame_lambda, // [1]
    float* __restrict__ ws_e,              // [F] per-face energy
    float* __restrict__ out,               // [0]=loss
    int F)
{
    const int t    = blockIdx.x * blockDim.x + threadIdx.x;
    const int base = t * 4;

    const float mu  = lame_mu[0];
    const float lam = lame_lambda[0];

    float esum = 0.0f;

    if (base + 3 < F) {
        const i4* fptr = reinterpret_cast<const i4*>(faces + 3 * base);
        const i4 fa = NT_LOAD(fptr + 0);
        const i4 fb = NT_LOAD(fptr + 1);
        const i4 fc = NT_LOAD(fptr + 2);
        const int idx[4][3] = {
            { fa.x, fa.y, fa.z },
            { fa.w, fb.x, fb.y },
            { fb.z, fb.w, fc.x },
            { fc.y, fc.z, fc.w },
        };

        const f4* mptr = reinterpret_cast<const f4*>(Dm_inv + 4 * base);
        f4 m[4];
        #pragma unroll
        for (int k = 0; k < 4; ++k) m[k] = NT_LOAD(mptr + k);

        const f4 area = NT_LOAD(reinterpret_cast<const f4*>(f_area + base));
        const float ar[4] = { area.x, area.y, area.z, area.w };

        // issue all 12 vertex gathers (cached: pred_pos has ~6x reuse)
        float px[4][3], py[4][3], pz[4][3];
        #pragma unroll
        for (int k = 0; k < 4; ++k) {
            #pragma unroll
            for (int j = 0; j < 3; ++j) {
                const int vi = idx[k][j];
                px[k][j] = pred_pos[3 * vi + 0];
                py[k][j] = pred_pos[3 * vi + 1];
                pz[k][j] = pred_pos[3 * vi + 2];
            }
        }

        f4 ev;
        #pragma unroll
        for (int k = 0; k < 4; ++k) {
            const float d0x = px[k][0] - px[k][2], d0y = py[k][0] - py[k][2], d0z = pz[k][0] - pz[k][2];
            const float d1x = px[k][1] - px[k][2], d1y = py[k][1] - py[k][2], d1z = pz[k][1] - pz[k][2];

            const float m00 = m[k].x, m01 = m[k].y, m10 = m[k].z, m11 = m[k].w;

            const float F0x = d0x * m00 + d1x * m10;
            const float F0y = d0y * m00 + d1y * m10;
            const float F0z = d0z * m00 + d1z * m10;
            const float F1x = d0x * m01 + d1x * m11;
            const float F1y = d0y * m01 + d1y * m11;
            const float F1z = d0z * m01 + d1z * m11;

            const float a = F0x * F0x + F0y * F0y + F0z * F0z;
            const float b = F0x * F1x + F0y * F1y + F0z * F1z;
            const float c = F1x * F1x + F1y * F1y + F1z * F1z;
            const float G00 = 0.5f * (a - 1.0f);
            const float G01 = 0.5f * b;
            const float G11 = 0.5f * (c - 1.0f);
            const float tr  = G00 + G11;

            const float density = mu * (G00 * G00 + 2.0f * G01 * G01 + G11 * G11)
                                + 0.5f * lam * tr * tr;

            const float e = ar[k] * THICKNESS * density;
            esum += e;
            ((float*)&ev)[k] = e;
        }
        *reinterpret_cast<f4*>(ws_e + base) = ev;
    } else if (base < F) {
        for (int f = base; f < F; ++f) {
            const int i0 = faces[3 * f + 0];
            const int i1 = faces[3 * f + 1];
            const int i2 = faces[3 * f + 2];

            const float v0x = pred_pos[3 * i0 + 0], v0y = pred_pos[3 * i0 + 1], v0z = pred_pos[3 * i0 + 2];
            const float v1x = pred_pos[3 * i1 + 0], v1y = pred_pos[3 * i1 + 1], v1z = pred_pos[3 * i1 + 2];
            const float v2x = pred_pos[3 * i2 + 0], v2y = pred_pos[3 * i2 + 1], v2z = pred_pos[3 * i2 + 2];

            const float d0x = v0x - v2x, d0y = v0y - v2y, d0z = v0z - v2z;
            const float d1x = v1x - v2x, d1y = v1y - v2y, d1z = v1z - v2z;

            const float m00 = Dm_inv[4 * f + 0], m01 = Dm_inv[4 * f + 1];
            const float m10 = Dm_inv[4 * f + 2], m11 = Dm_inv[4 * f + 3];

            const float F0x = d0x * m00 + d1x * m10;
            const float F0y = d0y * m00 + d1y * m10;
            const float F0z = d0z * m00 + d1z * m10;
            const float F1x = d0x * m01 + d1x * m11;
            const float F1y = d0y * m01 + d1y * m11;
            const float F1z = d0z * m01 + d1z * m11;

            const float a = F0x * F0x + F0y * F0y + F0z * F0z;
            const float b = F0x * F1x + F0y * F1y + F0z * F1z;
            const float c = F1x * F1x + F1y * F1y + F1z * F1z;
            const float G00 = 0.5f * (a - 1.0f);
            const float G01 = 0.5f * b;
            const float G11 = 0.5f * (c - 1.0f);
            const float tr  = G00 + G11;

            const float density = mu * (G00 * G00 + 2.0f * G01 * G01 + G11 * G11)
                                + 0.5f * lam * tr * tr;

            const float e = f_area[f] * THICKNESS * density;
            esum += e;
            ws_e[f] = e;
        }
    }

    // block reduction of esum -> loss
    float v = esum;
    #pragma unroll
    for (int off = 32; off > 0; off >>= 1)
        v += __shfl_down(v, off, 64);

    __shared__ float wsum[4];
    const int lane = threadIdx.x & 63;
    const int wave = threadIdx.x >> 6;
    if (lane == 0) wsum[wave] = v;
    __syncthreads();
    if (threadIdx.x == 0) {
        atomicAdd(&out[0], wsum[0] + wsum[1] + wsum[2] + wsum[3]);
    }
}

// K2: pure scatter. One thread per (face,slot): coalesced index read, coalesced
// energy read (3 adjacent threads share one e -> L1 broadcast), one atomicAdd.
// Minimal VGPRs -> max occupancy -> max outstanding atomics.
__global__ __launch_bounds__(256) void scatter_k2(
    const int*   __restrict__ faces,  // [F*3] flat
    const float* __restrict__ ws_e,   // [F]
    float* __restrict__ out,          // [1..V]
    int N)                            // N = 3*F
{
    const int t = blockIdx.x * blockDim.x + threadIdx.x;
    if (t < N) {
        const int   v  = faces[t];
        const float e3 = ws_e[t / 3] * (1.0f / 3.0f);
        atomicAdd(&out[1 + v], e3);
    }
}

extern "C" void kernel_launch(void* const* d_in, const int* in_sizes, int n_in,
                              void* d_out, int out_size, void* d_ws, size_t ws_size,
                              hipStream_t stream) {
    const float* pred_pos    = (const float*)d_in[0];
    const int*   faces       = (const int*)  d_in[1];
    const float* Dm_inv      = (const float*)d_in[2];
    const float* f_area      = (const float*)d_in[3];
    const float* lame_mu     = (const float*)d_in[4];
    const float* lame_lambda = (const float*)d_in[5];
    float* out  = (float*)d_out;
    float* ws_e = (float*)d_ws;

    const int F = in_sizes[1] / 3;
    const int N = 3 * F;

    // atomics accumulate into d_out -> must start at zero (harness poisons 0xAA)
    (void)hipMemsetAsync(d_out, 0, (size_t)out_size * sizeof(float), stream);

    const int block = 256;
    {
        const int threads = (F + 3) / 4;
        const int grid    = (threads + block - 1) / block;
        energy_k1<<<grid, block, 0, stream>>>(
            pred_pos, faces, Dm_inv, f_area, lame_mu, lame_lambda, ws_e, out, F);
    }
    {
        const int grid = (N + block - 1) / block;
        scatter_k2<<<grid, block, 0, stream>>>(faces, ws_e, out, N);
    }
}